// Round 9
// baseline (210.510 us; speedup 1.0000x reference)
//
#include <hip/hip_runtime.h>

#define E_EDGES   1000000
#define NNODES    2048
#define HCH       128
#define KP        136            // A/w1t row stride bf16: 128 z + 4 attr + bias + 3 zero
#define TILE      64
#define NTILES    (E_EDGES / TILE)   // 15625 exact
#define NSPREAD   8
#define GRID_GEMM 1024           // 4 blocks/CU resident
#define ZVEC      (32 * 2048 * 64 / 4)
#define ZBLK      2048
#define WBLK      66             // 66*256 = 132*128 w1t transpose elements

typedef short  shortx8 __attribute__((ext_vector_type(8)));
typedef float  floatx4 __attribute__((ext_vector_type(4)));

__device__ __forceinline__ unsigned short f2bf(float f) {
  union { float f; unsigned int u; } v; v.f = f;
  unsigned int r = (v.u + 0x7fffu + ((v.u >> 16) & 1u)) >> 16;
  return (unsigned short)r;
}
__device__ __forceinline__ void cfence() { asm volatile("" ::: "memory"); }
// lgkm-only barrier: LDS writes visible; vmem prefetches stay in flight.
__device__ __forceinline__ void bar_lds() {
  asm volatile("s_waitcnt lgkmcnt(0)" ::: "memory");
  __builtin_amdgcn_s_barrier();
  cfence();
}

// ---------------------------------------------------------------- prep ----
__global__ void k_prep(const float* __restrict__ z, const float* __restrict__ W1,
                       const float* __restrict__ b1,
                       unsigned short* __restrict__ zb, unsigned short* __restrict__ w1t,
                       float* __restrict__ gstats) {
  int bid = blockIdx.x;
  if (bid < ZBLK) {
    const float4* z4 = (const float4*)z;
    ushort4* zb4 = (ushort4*)zb;
    for (int i = bid * 256 + threadIdx.x; i < ZVEC; i += ZBLK * 256) {
      float4 v = z4[i];
      ushort4 o;
      o.x = f2bf(v.x); o.y = f2bf(v.y); o.z = f2bf(v.z); o.w = f2bf(v.w);
      zb4[i] = o;
    }
  } else if (bid < ZBLK + WBLK) {
    int idx = (bid - ZBLK) * 256 + threadIdx.x;   // 0..16895 = 132*128
    int k = idx >> 7, n = idx & 127;              // coalesced read of W1
    w1t[n * KP + k] = f2bf(W1[idx]);
  } else {
    int tid = threadIdx.x;
    if (tid < 512) {   // pad k=132..135: bias at 132, zeros after
      int n = tid >> 2, kp = 132 + (tid & 3);
      w1t[n * KP + kp] = (kp == 132) ? f2bf(b1[n]) : (unsigned short)0;
    }
    for (int i = tid; i < NSPREAD * 2 * HCH; i += 256) gstats[i] = 0.f;
  }
}

// ---------------------------------------------------------------- gemm ----
// R8 structure (occupancy-4, channel-quarter waves, acc-reuse, 1 lgkm-only
// barrier/tile) + COALESCED staging: 8 lanes = one full 128-B zb row, so each
// gather instruction touches 16 fully-consumed cache lines (was 64 partial),
// and ds_write_b128 rows hit all 32 banks conflict-free (was 4-way).
// Thread (lane) handles edges ea = w*8+(lane>>3), eb = ea+32; chunk = lane&7.
template<bool OUT>
__global__ __launch_bounds__(256, 4)
void k_gemm(const unsigned short* __restrict__ zb,
            const unsigned short* __restrict__ w1t,
            const int* __restrict__ ei,
            const float* __restrict__ attr,
            float* __restrict__ gstats,
            const float* __restrict__ gamma,
            const float* __restrict__ beta,
            const float* __restrict__ W2,
            const float* __restrict__ b2,
            float* __restrict__ out) {
  __shared__ __align__(16) unsigned short A[2][TILE * KP];   // 34816 B
  __shared__ float po[2][4][TILE];                           //  2048 B

  const int tid  = threadIdx.x;
  const int lane = tid & 63;
  const int w    = tid >> 6;      // channel quarter
  const int l15  = lane & 15;
  const int quad = lane >> 4;
  const int ea   = w * 8 + (lane >> 3);   // first edge this thread stages
  const int eb   = ea + 32;               // second edge
  const int ch   = lane & 7;              // 16B chunk within a 128B row

  // ---- B fragments: 2 n-tiles x 5 k-steps for this wave's 32 channels
  shortx8 bfr[2][4], bfr4[2];
#pragma unroll
  for (int nt = 0; nt < 2; ++nt) {
    const unsigned short* bp = w1t + (w * 32 + nt * 16 + l15) * KP;
#pragma unroll
    for (int kk = 0; kk < 4; ++kk)
      bfr[nt][kk] = *(const shortx8*)(bp + kk * 32 + quad * 8);
    bfr4[nt] = (quad == 0) ? *(const shortx8*)(bp + 128)
                           : (shortx8){0, 0, 0, 0, 0, 0, 0, 0};
  }

  float eaf[2], ebb[2], ew2[2], b2v = 0.f;
  float ssum[2] = {0.f, 0.f}, ssq[2] = {0.f, 0.f};
  if (OUT) {
#pragma unroll
    for (int nt = 0; nt < 2; ++nt) {
      int c = w * 32 + nt * 16 + l15;
      float S = 0.f, Q = 0.f;
#pragma unroll
      for (int i = 0; i < NSPREAD; ++i) {
        S += gstats[i * 2 * HCH + c];
        Q += gstats[i * 2 * HCH + HCH + c];
      }
      float mu   = S * (1.0f / (float)E_EDGES);
      float var  = Q * (1.0f / (float)E_EDGES) - mu * mu;
      float rstd = rsqrtf(var + 1e-5f);
      float a = gamma[c] * rstd;
      eaf[nt] = a;
      ebb[nt] = beta[c] - mu * a;
      ew2[nt] = W2[c];
    }
    b2v = b2[0];
  }

  // ---- one-time: constant bias block (k=132..135) in both buffers
  if (tid < 128) {
    int b = tid >> 6, r = tid & 63;
    ushort4 bl; bl.x = 0x3F80; bl.y = 0; bl.z = 0; bl.w = 0;
    *(ushort4*)(&A[b][0] + r * KP + 132) = bl;
  }

  auto rows_of = [&](int s_a, int d_a, int s_b, int d_b,
                     unsigned& r0, unsigned& r1, unsigned& r2, unsigned& r3) {
    r0 = (unsigned)s_a;
    r1 = (unsigned)s_b;
    r2 = ((unsigned)s_a & ~(unsigned)(NNODES - 1)) | ((unsigned)d_a & (NNODES - 1));
    r3 = ((unsigned)s_b & ~(unsigned)(NNODES - 1)) | ((unsigned)d_b & (NNODES - 1));
  };

  // ---- prologue: stage t0; gather(t1)->g, attr(t1)->av; ei(t2)->sa..db
  const int t0 = blockIdx.x;
  uint4 g0, g1, g2, g3;
  float4 av;
  int sa, da, sb, db;
  {
    int s0a = ei[t0 * TILE + ea], d0a = ei[E_EDGES + t0 * TILE + ea];
    int s0b = ei[t0 * TILE + eb], d0b = ei[E_EDGES + t0 * TILE + eb];
    if (w == 0) av = ((const float4*)attr)[t0 * TILE + tid];
    unsigned r0, r1, r2, r3;
    rows_of(s0a, d0a, s0b, d0b, r0, r1, r2, r3);
    g0 = *(const uint4*)(zb + (size_t)r0 * 64 + ch * 8);
    g1 = *(const uint4*)(zb + (size_t)r1 * 64 + ch * 8);
    g2 = *(const uint4*)(zb + (size_t)r2 * 64 + ch * 8);
    g3 = *(const uint4*)(zb + (size_t)r3 * 64 + ch * 8);
    *(uint4*)(&A[0][0] + ea * KP + ch * 8)      = g0;
    *(uint4*)(&A[0][0] + eb * KP + ch * 8)      = g1;
    *(uint4*)(&A[0][0] + ea * KP + 64 + ch * 8) = g2;
    *(uint4*)(&A[0][0] + eb * KP + 64 + ch * 8) = g3;
    if (w == 0) {
      ushort4 a0; a0.x = f2bf(av.x); a0.y = f2bf(av.y);
      a0.z = f2bf(av.z); a0.w = f2bf(av.w);
      *(ushort4*)(&A[0][0] + tid * KP + 128) = a0;
    }
    // t1 gather into regs
    int t1 = t0 + GRID_GEMM;
    int s1a = ei[t1 * TILE + ea], d1a = ei[E_EDGES + t1 * TILE + ea];
    int s1b = ei[t1 * TILE + eb], d1b = ei[E_EDGES + t1 * TILE + eb];
    rows_of(s1a, d1a, s1b, d1b, r0, r1, r2, r3);
    g0 = *(const uint4*)(zb + (size_t)r0 * 64 + ch * 8);
    g1 = *(const uint4*)(zb + (size_t)r1 * 64 + ch * 8);
    g2 = *(const uint4*)(zb + (size_t)r2 * 64 + ch * 8);
    g3 = *(const uint4*)(zb + (size_t)r3 * 64 + ch * 8);
    if (w == 0) av = ((const float4*)attr)[t1 * TILE + tid];
    // t2 ei into regs
    int t2 = t0 + 2 * GRID_GEMM;
    sa = ei[t2 * TILE + ea]; da = ei[E_EDGES + t2 * TILE + ea];
    sb = ei[t2 * TILE + eb]; db = ei[E_EDGES + t2 * TILE + eb];
  }
  bar_lds();

  int pp = 0, sl = 0;
  for (int tile = t0; ; ) {
    const bool more = (tile + GRID_GEMM) < NTILES;

    if (more) {
      // stage t+1 from prefetched regs into the idle buffer (coalesced rows)
      *(uint4*)(&A[pp ^ 1][0] + ea * KP + ch * 8)      = g0;
      *(uint4*)(&A[pp ^ 1][0] + eb * KP + ch * 8)      = g1;
      *(uint4*)(&A[pp ^ 1][0] + ea * KP + 64 + ch * 8) = g2;
      *(uint4*)(&A[pp ^ 1][0] + eb * KP + 64 + ch * 8) = g3;
      if (w == 0) {
        ushort4 a0; a0.x = f2bf(av.x); a0.y = f2bf(av.y);
        a0.z = f2bf(av.z); a0.w = f2bf(av.w);
        *(ushort4*)(&A[pp ^ 1][0] + tid * KP + 128) = a0;
      }
      // gather t+2 from in-flight ei regs; refill ei for t+3
      unsigned r0, r1, r2, r3;
      rows_of(sa, da, sb, db, r0, r1, r2, r3);
      g0 = *(const uint4*)(zb + (size_t)r0 * 64 + ch * 8);
      g1 = *(const uint4*)(zb + (size_t)r1 * 64 + ch * 8);
      g2 = *(const uint4*)(zb + (size_t)r2 * 64 + ch * 8);
      g3 = *(const uint4*)(zb + (size_t)r3 * 64 + ch * 8);
      int tn2 = tile + 2 * GRID_GEMM; if (tn2 > NTILES - 1) tn2 = NTILES - 1;
      if (w == 0) av = ((const float4*)attr)[tn2 * TILE + tid];
      int tn3 = tile + 3 * GRID_GEMM; if (tn3 > NTILES - 1) tn3 = NTILES - 1;
      sa = ei[tn3 * TILE + ea]; da = ei[E_EDGES + tn3 * TILE + ea];
      sb = ei[tn3 * TILE + eb]; db = ei[E_EDGES + tn3 * TILE + eb];
    }

    // ---- MFMA: 4 edge m-tiles sequentially, acc[2] reused
    const unsigned short* Ar = &A[pp][0];
#pragma unroll
    for (int mt = 0; mt < 4; ++mt) {
      const unsigned short* ap = Ar + (mt * 16 + l15) * KP;
      shortx8 afr[4], a4;
#pragma unroll
      for (int kk = 0; kk < 4; ++kk)
        afr[kk] = *(const shortx8*)(ap + kk * 32 + quad * 8);
      a4 = (quad == 0) ? *(const shortx8*)(ap + 128)
                       : (shortx8){0, 0, 0, 0, 0, 0, 0, 0};

      floatx4 acc[2];
      acc[0] = (floatx4){0.f, 0.f, 0.f, 0.f};
      acc[1] = (floatx4){0.f, 0.f, 0.f, 0.f};
#pragma unroll
      for (int kk = 0; kk < 4; ++kk)
#pragma unroll
        for (int nt = 0; nt < 2; ++nt)
          acc[nt] = __builtin_amdgcn_mfma_f32_16x16x32_bf16(
              afr[kk], bfr[nt][kk], acc[nt], 0, 0, 0);
#pragma unroll
      for (int nt = 0; nt < 2; ++nt)
        acc[nt] = __builtin_amdgcn_mfma_f32_16x16x32_bf16(
            a4, bfr4[nt], acc[nt], 0, 0, 0);

      // per-mt epilogue. C/D: col=l15 (channel), row=quad*4+r (edge in m-tile)
      if (!OUT) {
#pragma unroll
        for (int nt = 0; nt < 2; ++nt) {
          float s = 0.f, qq = 0.f;
#pragma unroll
          for (int r = 0; r < 4; ++r) {
            float h = acc[nt][r];
            s += h; qq += h * h;
          }
          ssum[nt] += s; ssq[nt] += qq;
        }
      } else {
#pragma unroll
        for (int r = 0; r < 4; ++r) {
          float t = 0.f;
#pragma unroll
          for (int nt = 0; nt < 2; ++nt) {
            float h = acc[nt][r];
            float p = fmaf(eaf[nt], h, ebb[nt]);
            p = (p >= 0.f) ? p : 0.2f * p;
            t = fmaf(ew2[nt], p, t);
          }
          t += __shfl_xor(t, 1);
          t += __shfl_xor(t, 2);
          t += __shfl_xor(t, 4);
          t += __shfl_xor(t, 8);     // sum over this wave's 32 channels
          if (l15 == 0)
            po[sl][w][mt * 16 + quad * 4 + r] = t;
        }
      }
    }

    if (more || OUT) bar_lds();      // A[pp^1]+po visible; gathers stay in flight

    if (OUT && tid < TILE)
      out[tile * TILE + tid] = po[sl][0][tid] + po[sl][1][tid] +
                               po[sl][2][tid] + po[sl][3][tid] + b2v;

    if (!more) break;
    pp ^= 1; sl ^= 1;
    tile += GRID_GEMM;
  }

  if (!OUT) {   // flush: quads hold disjoint edge subsets; reduce, one atomic set
    float* gs = gstats + (blockIdx.x & (NSPREAD - 1)) * 2 * HCH;
#pragma unroll
    for (int nt = 0; nt < 2; ++nt) {
      float s = ssum[nt], qq = ssq[nt];
      s += __shfl_xor(s, 16); s += __shfl_xor(s, 32);
      qq += __shfl_xor(qq, 16); qq += __shfl_xor(qq, 32);
      if (quad == 0) {
        int c = w * 32 + nt * 16 + l15;
        atomicAdd(&gs[c], s);
        atomicAdd(&gs[HCH + c], qq);
      }
    }
  }
}

// -------------------------------------------------------------- launch ----
extern "C" void kernel_launch(void* const* d_in, const int* in_sizes, int n_in,
                              void* d_out, int out_size, void* d_ws, size_t ws_size,
                              hipStream_t stream) {
  const float* z     = (const float*)d_in[0];
  const float* attr  = (const float*)d_in[1];
  const float* W1    = (const float*)d_in[2];
  const float* b1    = (const float*)d_in[3];
  const float* gamma = (const float*)d_in[4];
  const float* beta  = (const float*)d_in[5];
  const float* W2    = (const float*)d_in[6];
  const float* b2    = (const float*)d_in[7];
  const int*   ei    = (const int*)d_in[8];
  float* out = (float*)d_out;

  char* ws = (char*)d_ws;
  unsigned short* zb  = (unsigned short*)ws;                 // 8,388,608 B
  unsigned short* w1t = (unsigned short*)(ws + 8388608);     //    34,816 B
  float* gstats       = (float*)(ws + 8423424);              //     8,192 B

  k_prep<<<ZBLK + WBLK + 1, 256, 0, stream>>>(z, W1, b1, zb, w1t, gstats);
  k_gemm<false><<<GRID_GEMM, 256, 0, stream>>>(zb, w1t, ei, attr, gstats,
                                               gamma, beta, W2, b2, nullptr);
  k_gemm<true><<<GRID_GEMM, 256, 0, stream>>>(zb, w1t, ei, attr, gstats,
                                              gamma, beta, W2, b2, out);
}